// Round 11
// baseline (1154.121 us; speedup 1.0000x reference)
//
#include <hip/hip_runtime.h>

typedef _Float16 half8 __attribute__((ext_vector_type(8)));
typedef _Float16 half4 __attribute__((ext_vector_type(4)));
typedef float floatx4 __attribute__((ext_vector_type(4)));
typedef float floatx16 __attribute__((ext_vector_type(16)));

static constexpr int BATCH = 1024;
static constexpr int NIN   = 512;    // in_features
static constexpr int MOUT  = 1024;   // out_features
static constexpr float LAMBD = 0.2f;
static constexpr float TOLF  = 1e-4f;
static constexpr int MAX_ITERS = 100;
static constexpr int MM = BATCH * MOUT;   // 1M elements

// 16x16x32 fragment swizzle (dec path): lane=(idx&15)|(((k>>3)&3)<<4)
__device__ __forceinline__ size_t swz(int idx, int k) {
    return ((((size_t)(idx >> 4) * 32 + (k >> 5)) * 64 +
             ((idx & 15) | (((k >> 3) & 3) << 4))) << 3) + (k & 7);
}

// 32x32x16 fragment swizzle (iteration GEMM) [HW-validated rounds 7-10]
__device__ __forceinline__ size_t swz32(int idx, int k) {
    return ((((size_t)(idx >> 5) * 64 + (k >> 4)) * 64 +
             ((idx & 31) | (((k >> 3) & 1) << 5))) << 3) + (k & 7);
}

__device__ __forceinline__ float shrinkf(float t) {
    float a = fabsf(t) - LAMBD;
    return a > 0.f ? copysignf(a, t) : 0.f;
}

// ---------------------------------------------------------------------------
// XCD-local 32-block barrier (rounds 3-8 proven; round-10 showed the RMW
// chain overlaps block-arrival stagger, so this is near-optimal). Stripe =
// one XCD (bid%8): stores L2-visible after vmcnt drain (write-through L1);
// one device-scope RMW arrive; relaxed spin; L1-only invalidate.
// ---------------------------------------------------------------------------
__device__ __forceinline__ void gbar32(int* cnt, int* gen, int seq) {
    __syncthreads();
    if (threadIdx.x == 0) {
        int old = atomicAdd(cnt, 1);
        if (old == seq * 32 - 1) {
            __hip_atomic_store(gen, seq, __ATOMIC_RELAXED,
                               __HIP_MEMORY_SCOPE_AGENT);
        } else {
            while (__hip_atomic_load(gen, __ATOMIC_RELAXED,
                                     __HIP_MEMORY_SCOPE_AGENT) < seq)
                __builtin_amdgcn_s_sleep(1);
        }
    }
    __syncthreads();
    asm volatile("buffer_inv sc0" ::: "memory");
}

// ---------------------------------------------------------------------------
__global__ __launch_bounds__(256) void zero_init(float* t, float* enc,
                                                 float* dec, float* ench_f,
                                                 float* encl_f, int* solved) {
    int i = blockIdx.x * 256 + threadIdx.x;
    if (i < MM) { t[i] = 0.f; enc[i] = 0.f; }
    if (i < MM / 2) { dec[i] = 0.f; ench_f[i] = 0.f; encl_f[i] = 0.f; }
    if (i < 4096) solved[i] = 0;   // barrier words live at solved+1088
}

// ---------------------------------------------------------------------------
// Th/Tl = 32x32-fragment-swizzled split-f16 of Minv (idx=n, k over 1024).
// ---------------------------------------------------------------------------
__global__ __launch_bounds__(256) void split_minv(const float* __restrict__ Minv,
                                                  _Float16* __restrict__ Th,
                                                  _Float16* __restrict__ Tl) {
    int g = blockIdx.x * 256 + threadIdx.x;   // 131072 threads
    int n = g & 1023, k0 = (g >> 10) << 3;
    half8 h, l;
    #pragma unroll
    for (int e = 0; e < 8; ++e) {
        float val = Minv[(size_t)(k0 + e) * MOUT + n];
        _Float16 hh = (_Float16)val;
        h[e] = hh;
        l[e] = (_Float16)(val - (float)hh);
    }
    size_t off = swz32(n, k0);
    *(half8*)&Th[off] = h;
    *(half8*)&Tl[off] = l;
}

// ---------------------------------------------------------------------------
// wsh/wsl = 16x16-swizzled split-f16 of weight (dec path).
// ---------------------------------------------------------------------------
__global__ __launch_bounds__(256) void split_w(const float* __restrict__ w,
                                               _Float16* __restrict__ wsh,
                                               _Float16* __restrict__ wsl) {
    int g = blockIdx.x * 256 + threadIdx.x;   // 65536 threads
    int n = g & 511, k0 = (g >> 9) << 3;
    half8 h, l;
    #pragma unroll
    for (int e = 0; e < 8; ++e) {
        float val = w[(size_t)(k0 + e) * NIN + n];
        _Float16 hh = (_Float16)val;
        h[e] = hh;
        l[e] = (_Float16)(val - (float)hh);
    }
    size_t off = swz(n, k0);
    *(half8*)&wsh[off] = h;
    *(half8*)&wsl[off] = l;
}

// ---------------------------------------------------------------------------
// adb = x @ w^T (fp32, once). Epilogue emits beff buffer 0 (32x32 swizzle).
// ---------------------------------------------------------------------------
__global__ __launch_bounds__(256) void gemm_adb(const float* __restrict__ x,
                                                const float* __restrict__ w,
                                                float* __restrict__ adb,
                                                _Float16* __restrict__ bh,
                                                _Float16* __restrict__ bl) {
    __shared__ float As[16][68];
    __shared__ float Bs[16][68];
    const int tid = threadIdx.x;
    const int i0 = (blockIdx.x >> 4) * 64, j0 = (blockIdx.x & 15) * 64;
    const int tx = tid & 15, ty = tid >> 4;
    const int lr = tid >> 2, lk = (tid & 3) << 2;
    float acc[4][4] = {};
    for (int k0 = 0; k0 < NIN; k0 += 16) {
        float4 a4 = *(const float4*)&x[(i0 + lr) * NIN + k0 + lk];
        As[lk + 0][lr] = a4.x; As[lk + 1][lr] = a4.y;
        As[lk + 2][lr] = a4.z; As[lk + 3][lr] = a4.w;
        float4 b4 = *(const float4*)&w[(j0 + lr) * NIN + k0 + lk];
        Bs[lk + 0][lr] = b4.x; Bs[lk + 1][lr] = b4.y;
        Bs[lk + 2][lr] = b4.z; Bs[lk + 3][lr] = b4.w;
        __syncthreads();
        #pragma unroll
        for (int kk = 0; kk < 16; ++kk) {
            float4 a_ = *(const float4*)&As[kk][ty << 2];
            float4 b_ = *(const float4*)&Bs[kk][tx << 2];
            #pragma unroll
            for (int r = 0; r < 4; ++r) {
                float av = r == 0 ? a_.x : r == 1 ? a_.y : r == 2 ? a_.z : a_.w;
                acc[r][0] = fmaf(av, b_.x, acc[r][0]);
                acc[r][1] = fmaf(av, b_.y, acc[r][1]);
                acc[r][2] = fmaf(av, b_.z, acc[r][2]);
                acc[r][3] = fmaf(av, b_.w, acc[r][3]);
            }
        }
        __syncthreads();
    }
    const int k4 = j0 + (tx << 2);
    #pragma unroll
    for (int r = 0; r < 4; ++r) {
        const int row = i0 + (ty << 2) + r;
        *(float4*)&adb[(size_t)row * MOUT + k4] =
            make_float4(acc[r][0], acc[r][1], acc[r][2], acc[r][3]);
        half4 h, l;
        #pragma unroll
        for (int e = 0; e < 4; ++e) {
            _Float16 hh = (_Float16)acc[r][e];
            h[e] = hh;
            l[e] = (_Float16)(acc[r][e] - (float)hh);
        }
        size_t off = swz32(row, k4);
        *(half4*)&bh[off] = h;
        *(half4*)&bl[off] = l;
    }
}

// ---------------------------------------------------------------------------
// FUSED persistent ADMM loop v8 = round-8 structure (best verified, 1040us)
// + depth-6 software-pipelined beff prefetch (the ONLY change). Occupancy is
// LDS-capped at 1 block/CU, so the +48 prefetch VGPRs are free; full unroll
// keeps all rotation indices compile-time (no scratch). 12 loads stay in
// flight continuously (~300-400cy cover vs ~200-300cy L2 latency), removing
// the per-unroll-body stall of the compiler's own 4-deep schedule.
// ---------------------------------------------------------------------------
__global__ __launch_bounds__(512, 1)
void admm_loop(const float* __restrict__ adb, float* __restrict__ part,
               _Float16* __restrict__ bh0, _Float16* __restrict__ bl0,
               _Float16* __restrict__ bh1, _Float16* __restrict__ bl1,
               const _Float16* __restrict__ Th, const _Float16* __restrict__ Tl,
               float* __restrict__ enc, _Float16* __restrict__ ench,
               _Float16* __restrict__ encl, int* __restrict__ bar) {
    const int bid = blockIdx.x;
    const int tid = threadIdx.x, lane = tid & 63;
    const int w = tid >> 6;                // wave 0..7
    const int bt = w >> 1;                 // batch tile 0..3
    const int kh = w & 1;                  // K-half
    const int mt = bid & 7, nt = bid >> 3;
    const int n0 = nt << 5, m0 = mt << 7;
    const int hn = lane >> 5;              // n-half selector
    const int brow = m0 + (bt << 5) + (lane & 31);
    const int btile = (mt << 2) + bt;      // beff 32-row tile

    __shared__ _Float16 Bs[128 * 512];     // 128 KB Minv slice: chunk=kc*2+hl
    __shared__ float4 sc4[4][4][64];       // 16 KB k-half exchange, lane-contig
    __shared__ unsigned char sfroz[128];   // sticky frozen mask (block-local)

    if (tid < 128) sfroz[tid] = 0;

    // one-time Minv staging: 128 chunks of 1 KB (16 per wave)
    #pragma unroll
    for (int q = 0; q < 16; ++q) {
        const int chunk = (w << 4) + q;
        const int kc = chunk >> 1, hl = chunk & 1;
        const _Float16* src = (hl ? Tl : Th) +
            (((size_t)((nt << 6) + kc)) << 9) + ((size_t)lane << 3);
        __builtin_amdgcn_global_load_lds(
            (const __attribute__((address_space(1))) void*)src,
            (__attribute__((address_space(3))) void*)&Bs[(size_t)chunk << 9],
            16, 0, 0);
    }
    __syncthreads();

    int* gcnt = bar + (mt << 5);
    int* ggen = bar + (mt << 5) + 16;

    // decision geometry: wave handles rows m0+w*16..+15; 4 lanes per row
    const int drow_l = (w << 4) + (lane >> 2);     // row-in-stripe 0..127
    const int dq = (lane & 3) << 3;                // first float2 col
    const float* dbase0 = part + ((((size_t)(m0 + drow_l)) << 6) + (dq << 1));

    // register-resident state (kh==0 waves): n = n0 + 8*r4 + 4*hn + e
    float treg[16] = {};
    float adbreg[16];
    #pragma unroll
    for (int r4 = 0; r4 < 4; ++r4) {
        const int nb = n0 + (r4 << 3) + (hn << 2);
        float4 a4 = *(const float4*)&adb[(size_t)brow * MOUT + nb];
        adbreg[(r4 << 2) + 0] = a4.x; adbreg[(r4 << 2) + 1] = a4.y;
        adbreg[(r4 << 2) + 2] = a4.z; adbreg[(r4 << 2) + 3] = a4.w;
    }

    int it = 0;
    for (; it < MAX_ITERS; ++it) {
        const _Float16* rbh = (it & 1) ? bh1 : bh0;
        const _Float16* rbl = (it & 1) ? bl1 : bl0;
        _Float16* wbh = (it & 1) ? bh0 : bh1;
        _Float16* wbl = (it & 1) ? bl0 : bl1;
        const int pw = it & 1;             // part write buffer

        // ---- issue decision loads (iter it-1 partials, buffer !pw) early
        float4 dp0, dp1, dp2, dp3;
        if (it) {
            const float* pb = dbase0 + ((size_t)(pw ^ 1) << 16);
            dp0 = *(const float4*)(pb + 0);
            dp1 = *(const float4*)(pb + 4);
            dp2 = *(const float4*)(pb + 8);
            dp3 = *(const float4*)(pb + 12);
        }

        // ============ PHASE A: 32x32x16 gemm, depth-6 prefetch rotation ====
        floatx16 accA = {}, accB = {}, accC = {};
        const int kc0 = kh << 5;
        const size_t base =
            (((size_t)(btile << 6) + kc0) << 9) + ((size_t)lane << 3);
        half8 pbh[6], pbl[6];
        #pragma unroll
        for (int d = 0; d < 6; ++d) {
            pbh[d] = *(const half8*)&rbh[base + ((size_t)d << 9)];
            pbl[d] = *(const half8*)&rbl[base + ((size_t)d << 9)];
        }
        #pragma unroll
        for (int kcp = 0; kcp < 32; ++kcp) {
            const int d = kcp % 6;         // compile-time (full unroll)
            const half8 bhf = pbh[d];
            const half8 blf = pbl[d];
            if (kcp < 26) {
                pbh[d] = *(const half8*)&rbh[base + ((size_t)(kcp + 6) << 9)];
                pbl[d] = *(const half8*)&rbl[base + ((size_t)(kcp + 6) << 9)];
            }
            const int kc = kc0 + kcp;
            const half8 ah = *(const half8*)&Bs[((kc << 1) << 9) + (lane << 3)];
            const half8 al = *(const half8*)&Bs[(((kc << 1) | 1) << 9) + (lane << 3)];
            accA = __builtin_amdgcn_mfma_f32_32x32x16_f16(al, bhf, accA, 0, 0, 0);
            accB = __builtin_amdgcn_mfma_f32_32x32x16_f16(ah, blf, accB, 0, 0, 0);
            accC = __builtin_amdgcn_mfma_f32_32x32x16_f16(ah, bhf, accC, 0, 0, 0);
        }
        if (kh) {   // publish k-half-1 partial (conflict-free layout)
            #pragma unroll
            for (int r4 = 0; r4 < 4; ++r4) {
                float4 v;
                v.x = (accA[(r4 << 2) + 0] + accB[(r4 << 2) + 0]) + accC[(r4 << 2) + 0];
                v.y = (accA[(r4 << 2) + 1] + accB[(r4 << 2) + 1]) + accC[(r4 << 2) + 1];
                v.z = (accA[(r4 << 2) + 2] + accB[(r4 << 2) + 2]) + accC[(r4 << 2) + 2];
                v.w = (accA[(r4 << 2) + 3] + accB[(r4 << 2) + 3]) + accC[(r4 << 2) + 3];
                sc4[bt][r4][lane] = v;
            }
        }

        // ---- decision reduce for iter it-1 (hidden under GEMM latency)
        if (it) {
            float rdx = ((dp0.x + dp0.z) + (dp1.x + dp1.z)) +
                        ((dp2.x + dp2.z) + (dp3.x + dp3.z));
            float rx  = ((dp0.y + dp0.w) + (dp1.y + dp1.w)) +
                        ((dp2.y + dp2.w) + (dp3.y + dp3.w));
            rdx += __shfl_xor(rdx, 1); rdx += __shfl_xor(rdx, 2);
            rx  += __shfl_xor(rx, 1);  rx  += __shfl_xor(rx, 2);
            if (rdx < TOLF * TOLF * rx && (lane & 3) == 0)
                sfroz[drow_l] = 1;         // sticky set, never cleared
        }
        __syncthreads();                   // publishes sc4 AND sfroz

        // ---- stripe-uniform exact early exit (block-local ballot)
        bool f0 = sfroz[lane] != 0, f1 = sfroz[64 + lane] != 0;
        if ((__ballot(f0) & __ballot(f1)) == ~0ull) break;

        // ============ fused update (kh==0 waves, active rows) ==============
        const bool sflag = sfroz[(bt << 5) + (lane & 31)] != 0;
        if (kh == 0 && !sflag) {
            float dx2 = 0.f, x2 = 0.f;
            #pragma unroll
            for (int r4 = 0; r4 < 4; ++r4) {
                float4 p1 = sc4[bt][r4][lane];
                float pa[4] = {p1.x, p1.y, p1.z, p1.w};
                half4 h, l;
                #pragma unroll
                for (int e = 0; e < 4; ++e) {
                    const int r = (r4 << 2) + e;
                    float s0 = (accA[r] + accB[r]) + accC[r];
                    float xk = s0 + pa[e];            // p0 + p1 (ref order)
                    float t_ = treg[r];
                    float vprev = shrinkf(t_);
                    float uu = t_ - vprev;
                    float tn = xk + uu;               // = u + xk
                    float vv = shrinkf(tn);
                    float un = tn - vv;               // u_new
                    float d = vv - vprev;
                    dx2 += d * d;
                    x2 += vv * vv;
                    treg[r] = tn;
                    float nb_ = (adbreg[r] + vv) - un;
                    _Float16 hh = (_Float16)nb_;
                    h[e] = hh;
                    l[e] = (_Float16)(nb_ - (float)hh);
                }
                size_t off = swz32(brow, n0 + (r4 << 3) + (hn << 2));
                *(half4*)&wbh[off] = h;
                *(half4*)&wbl[off] = l;
            }
            // row partial over block's 32 n: lane^32 holds the other n-half
            dx2 += __shfl_xor(dx2, 32);
            x2  += __shfl_xor(x2, 32);
            if (hn == 0)
                *(float2*)&part[(((size_t)pw << 16) +
                                 (((size_t)brow) << 6) + ((size_t)nt << 1))] =
                    make_float2(dx2, x2);
        }
        gbar32(gcnt, ggen, it + 1);
    }

    // ---- final pending decision (rows converging at the last iteration)
    if (it == MAX_ITERS) {
        const float* pb = dbase0 + ((size_t)((MAX_ITERS - 1) & 1) << 16);
        float4 dp0 = *(const float4*)(pb + 0);
        float4 dp1 = *(const float4*)(pb + 4);
        float4 dp2 = *(const float4*)(pb + 8);
        float4 dp3 = *(const float4*)(pb + 12);
        float rdx = ((dp0.x + dp0.z) + (dp1.x + dp1.z)) +
                    ((dp2.x + dp2.z) + (dp3.x + dp3.z));
        float rx  = ((dp0.y + dp0.w) + (dp1.y + dp1.w)) +
                    ((dp2.y + dp2.w) + (dp3.y + dp3.w));
        rdx += __shfl_xor(rdx, 1); rdx += __shfl_xor(rdx, 2);
        rx  += __shfl_xor(rx, 1);  rx  += __shfl_xor(rx, 2);
        if (rdx < TOLF * TOLF * rx && (lane & 3) == 0)
            sfroz[drow_l] = 1;
        __syncthreads();
    }

    // ============ final flush: enc = shrink(t_frozen) for solved rows ======
    if (kh == 0 && sfroz[(bt << 5) + (lane & 31)]) {
        #pragma unroll
        for (int r4 = 0; r4 < 4; ++r4) {
            const int nb = n0 + (r4 << 3) + (hn << 2);
            float va[4]; half4 h, l;
            #pragma unroll
            for (int e = 0; e < 4; ++e) {
                float vv = shrinkf(treg[(r4 << 2) + e]);
                va[e] = vv;
                _Float16 hh = (_Float16)vv;
                h[e] = hh;
                l[e] = (_Float16)(vv - (float)hh);
            }
            *(float4*)&enc[(size_t)brow * MOUT + nb] =
                make_float4(va[0], va[1], va[2], va[3]);
            size_t off = swz(brow, nb);        // dec path keeps 16x16 swizzle
            *(half4*)&ench[off] = h;
            *(half4*)&encl[off] = l;
        }
    }
}

// ---------------------------------------------------------------------------
// dec = enc @ w, split-f16 MFMA (16x16 path), runs ONCE. Unchanged.
// ---------------------------------------------------------------------------
__global__ __launch_bounds__(256, 2)
void mfma_dec(const _Float16* __restrict__ Ahg, const _Float16* __restrict__ Alg,
              const _Float16* __restrict__ Bhg, const _Float16* __restrict__ Blg,
              float* __restrict__ out) {
    constexpr int NSTR = NIN;              // 512
    constexpr int NT = NSTR / 128;         // 4
    const int bid = blockIdx.x;
    const int c = bid & 7, t = bid >> 3;
    const int mt = t / NT, nt = t % NT;
    const int tid = threadIdx.x, lane = tid & 63;

    __shared__ _Float16 Ash[64 * 512];     // 64 KB

    const int wv = tid >> 6;
    const int wm = (tid >> 7) & 1, wn = (tid >> 6) & 1;
    const int kf0 = c << 2;

    #pragma unroll
    for (int i = 0; i < 16; ++i) {
        const int chunk = (wv << 4) + i;
        const int rt = chunk >> 3, kc = (chunk >> 1) & 3, hl = chunk & 1;
        const _Float16* src = (hl ? Alg : Ahg) +
            ((((size_t)((mt << 3) + rt) * 32 + kf0 + kc) << 9) + ((size_t)lane << 3));
        __builtin_amdgcn_global_load_lds(
            (const __attribute__((address_space(1))) void*)src,
            (__attribute__((address_space(3))) void*)&Ash[(size_t)chunk << 9],
            16, 0, 0);
    }
    __syncthreads();

    const int ct0 = nt * 8 + (wn << 2);
    const _Float16* pBh = Bhg + ((((size_t)ct0 * 32 + kf0) * 64 + lane) << 3);
    const _Float16* pBl = Blg + ((((size_t)ct0 * 32 + kf0) * 64 + lane) << 3);

    floatx4 acc[4][4] = {};
    #pragma unroll
    for (int s = 0; s < 4; ++s) {
        half8 bhf[4], blf[4];
        #pragma unroll
        for (int j = 0; j < 4; ++j) {
            bhf[j] = *(const half8*)(pBh + ((size_t)j << 14) + ((size_t)s << 9));
            blf[j] = *(const half8*)(pBl + ((size_t)j << 14) + ((size_t)s << 9));
        }
        half8 ah[4], al[4];
        #pragma unroll
        for (int i = 0; i < 4; ++i) {
            const int rt = (wm << 2) + i;
            ah[i] = *(const half8*)&Ash[((((rt << 2) + s) << 1) << 9) + (lane << 3)];
            al[i] = *(const half8*)&Ash[(((((rt << 2) + s) << 1) + 1) << 9) + (lane << 3)];
        }
        #pragma unroll
        for (int i = 0; i < 4; ++i)
            #pragma unroll
            for (int j = 0; j < 4; ++j) {
                acc[i][j] = __builtin_amdgcn_mfma_f32_16x16x32_f16(
                    ah[i], blf[j], acc[i][j], 0, 0, 0);
                acc[i][j] = __builtin_amdgcn_mfma_f32_16x16x32_f16(
                    al[i], bhf[j], acc[i][j], 0, 0, 0);
                acc[i][j] = __builtin_amdgcn_mfma_f32_16x16x32_f16(
                    ah[i], bhf[j], acc[i][j], 0, 0, 0);
            }
    }

    const int orow = (lane >> 4) << 2;
    #pragma unroll
    for (int i = 0; i < 4; ++i) {
        const int gr = (mt << 7) + (wm << 6) + (i << 4) + orow;
        #pragma unroll
        for (int j = 0; j < 4; ++j) {
            const int gc = nt * 128 + (wn << 6) + (j << 4) + (lane & 15);
            #pragma unroll
            for (int r = 0; r < 4; ++r)
                atomicAdd(&out[(size_t)(gr + r) * NSTR + gc], acc[i][j][r]);
        }
    }
}

// ---------------------------------------------------------------------------
extern "C" void kernel_launch(void* const* d_in, const int* in_sizes, int n_in,
                              void* d_out, int out_size, void* d_ws, size_t ws_size,
                              hipStream_t stream) {
    const float* x    = (const float*)d_in[0];
    const float* w    = (const float*)d_in[1];
    const float* Minv = (const float*)d_in[2];

    float* enc = (float*)d_out;          // encoded: 1024*1024
    float* dec = enc + MM;               // decoded: 1024*512

    // ws (floats): adb MM | beff buf1 (bh1,bl1) | part 2x256KB (in 2*MM) |
    // halves: bh0,bl0,Th,Tl,ench,encl MM, wsh,wsl MM/2 | barrier words.
    float* ws  = (float*)d_ws;
    float* adb = ws;
    _Float16* bh1 = (_Float16*)(ws + (size_t)MM);   // ping-pong buffer 1
    _Float16* bl1 = bh1 + (size_t)MM;
    float* part = ws + 2 * (size_t)MM;              // 2 x [1024][32] float2

    _Float16* bh0  = (_Float16*)(ws + 4 * (size_t)MM);
    _Float16* bl0  = bh0 + (size_t)MM;
    _Float16* Th   = bl0 + (size_t)MM;
    _Float16* Tl   = Th + (size_t)MM;
    _Float16* ench = Tl + (size_t)MM;
    _Float16* encl = ench + (size_t)MM;
    _Float16* wsh  = encl + (size_t)MM;
    _Float16* wsl  = wsh + (size_t)(NIN * MOUT);
    int* solved    = (int*)(wsl + (size_t)(NIN * MOUT));
    int* bar       = solved + 1088;      // 8 stripes x 32 ints (128 B) apart

    zero_init<<<(MM + 255) / 256, 256, 0, stream>>>((float*)bh1, enc, dec,
                                                    (float*)ench, (float*)encl,
                                                    solved);
    split_minv<<<512, 256, 0, stream>>>(Minv, Th, Tl);
    split_w<<<256, 256, 0, stream>>>(w, wsh, wsl);
    gemm_adb<<<256, 256, 0, stream>>>(x, w, adb, bh0, bl0);

    void* cargs[] = {(void*)&adb, (void*)&part,
                     (void*)&bh0, (void*)&bl0, (void*)&bh1, (void*)&bl1,
                     (void*)&Th,  (void*)&Tl,
                     (void*)&enc, (void*)&ench, (void*)&encl, (void*)&bar};
    // Cooperative launch used ONLY as a co-residency guarantee (deadlock
    // safety for the spin barriers); no grid.sync() is ever called.
    hipLaunchCooperativeKernel(reinterpret_cast<void*>(admm_loop),
                               dim3(256), dim3(512), cargs, 0, stream);

    mfma_dec<<<256, 256, 0, stream>>>(ench, encl, wsh, wsl, dec);
}

// Round 12
// 1035.797 us; speedup vs baseline: 1.1142x; 1.1142x over previous
//
#include <hip/hip_runtime.h>

typedef _Float16 half8 __attribute__((ext_vector_type(8)));
typedef _Float16 half4 __attribute__((ext_vector_type(4)));
typedef float floatx4 __attribute__((ext_vector_type(4)));
typedef float floatx16 __attribute__((ext_vector_type(16)));

static constexpr int BATCH = 1024;
static constexpr int NIN   = 512;    // in_features
static constexpr int MOUT  = 1024;   // out_features
static constexpr float LAMBD = 0.2f;
static constexpr float TOLF  = 1e-4f;
static constexpr int MAX_ITERS = 100;
static constexpr int MM = BATCH * MOUT;   // 1M elements

// 16x16x32 fragment swizzle (dec path): lane=(idx&15)|(((k>>3)&3)<<4)
__device__ __forceinline__ size_t swz(int idx, int k) {
    return ((((size_t)(idx >> 4) * 32 + (k >> 5)) * 64 +
             ((idx & 15) | (((k >> 3) & 3) << 4))) << 3) + (k & 7);
}

// 32x32x16 fragment swizzle (iteration GEMM) [HW-validated rounds 7-11]
__device__ __forceinline__ size_t swz32(int idx, int k) {
    return ((((size_t)(idx >> 5) * 64 + (k >> 4)) * 64 +
             ((idx & 31) | (((k >> 3) & 1) << 5))) << 3) + (k & 7);
}

__device__ __forceinline__ float shrinkf(float t) {
    float a = fabsf(t) - LAMBD;
    return a > 0.f ? copysignf(a, t) : 0.f;
}

// ---------------------------------------------------------------------------
// XCD-local 32-block barrier (rounds 3-8 proven; rounds 10/11 showed the RMW
// chain overlaps block-arrival stagger and manual alternatives regress).
// Stripe = one XCD (bid%8): stores L2-visible after vmcnt drain
// (write-through L1); one device-scope RMW arrive; relaxed spin; L1-only
// invalidate. ONE barrier per iteration.
// ---------------------------------------------------------------------------
__device__ __forceinline__ void gbar32(int* cnt, int* gen, int seq) {
    __syncthreads();
    if (threadIdx.x == 0) {
        int old = atomicAdd(cnt, 1);
        if (old == seq * 32 - 1) {
            __hip_atomic_store(gen, seq, __ATOMIC_RELAXED,
                               __HIP_MEMORY_SCOPE_AGENT);
        } else {
            while (__hip_atomic_load(gen, __ATOMIC_RELAXED,
                                     __HIP_MEMORY_SCOPE_AGENT) < seq)
                __builtin_amdgcn_s_sleep(1);
        }
    }
    __syncthreads();
    asm volatile("buffer_inv sc0" ::: "memory");
}

// ---------------------------------------------------------------------------
__global__ __launch_bounds__(256) void zero_init(float* t, float* enc,
                                                 float* dec, float* ench_f,
                                                 float* encl_f, int* solved) {
    int i = blockIdx.x * 256 + threadIdx.x;
    if (i < MM) { t[i] = 0.f; enc[i] = 0.f; }
    if (i < MM / 2) { dec[i] = 0.f; ench_f[i] = 0.f; encl_f[i] = 0.f; }
    if (i < 4096) solved[i] = 0;   // barrier words live at solved+1088
}

// ---------------------------------------------------------------------------
// Th/Tl = 32x32-fragment-swizzled split-f16 of Minv (idx=n, k over 1024).
// ---------------------------------------------------------------------------
__global__ __launch_bounds__(256) void split_minv(const float* __restrict__ Minv,
                                                  _Float16* __restrict__ Th,
                                                  _Float16* __restrict__ Tl) {
    int g = blockIdx.x * 256 + threadIdx.x;   // 131072 threads
    int n = g & 1023, k0 = (g >> 10) << 3;
    half8 h, l;
    #pragma unroll
    for (int e = 0; e < 8; ++e) {
        float val = Minv[(size_t)(k0 + e) * MOUT + n];
        _Float16 hh = (_Float16)val;
        h[e] = hh;
        l[e] = (_Float16)(val - (float)hh);
    }
    size_t off = swz32(n, k0);
    *(half8*)&Th[off] = h;
    *(half8*)&Tl[off] = l;
}

// ---------------------------------------------------------------------------
// wsh/wsl = 16x16-swizzled split-f16 of weight (dec path).
// ---------------------------------------------------------------------------
__global__ __launch_bounds__(256) void split_w(const float* __restrict__ w,
                                               _Float16* __restrict__ wsh,
                                               _Float16* __restrict__ wsl) {
    int g = blockIdx.x * 256 + threadIdx.x;   // 65536 threads
    int n = g & 511, k0 = (g >> 9) << 3;
    half8 h, l;
    #pragma unroll
    for (int e = 0; e < 8; ++e) {
        float val = w[(size_t)(k0 + e) * NIN + n];
        _Float16 hh = (_Float16)val;
        h[e] = hh;
        l[e] = (_Float16)(val - (float)hh);
    }
    size_t off = swz(n, k0);
    *(half8*)&wsh[off] = h;
    *(half8*)&wsl[off] = l;
}

// ---------------------------------------------------------------------------
// adb = x @ w^T (fp32, once). Epilogue emits beff buffer 0 (32x32 swizzle).
// ---------------------------------------------------------------------------
__global__ __launch_bounds__(256) void gemm_adb(const float* __restrict__ x,
                                                const float* __restrict__ w,
                                                float* __restrict__ adb,
                                                _Float16* __restrict__ bh,
                                                _Float16* __restrict__ bl) {
    __shared__ float As[16][68];
    __shared__ float Bs[16][68];
    const int tid = threadIdx.x;
    const int i0 = (blockIdx.x >> 4) * 64, j0 = (blockIdx.x & 15) * 64;
    const int tx = tid & 15, ty = tid >> 4;
    const int lr = tid >> 2, lk = (tid & 3) << 2;
    float acc[4][4] = {};
    for (int k0 = 0; k0 < NIN; k0 += 16) {
        float4 a4 = *(const float4*)&x[(i0 + lr) * NIN + k0 + lk];
        As[lk + 0][lr] = a4.x; As[lk + 1][lr] = a4.y;
        As[lk + 2][lr] = a4.z; As[lk + 3][lr] = a4.w;
        float4 b4 = *(const float4*)&w[(j0 + lr) * NIN + k0 + lk];
        Bs[lk + 0][lr] = b4.x; Bs[lk + 1][lr] = b4.y;
        Bs[lk + 2][lr] = b4.z; Bs[lk + 3][lr] = b4.w;
        __syncthreads();
        #pragma unroll
        for (int kk = 0; kk < 16; ++kk) {
            float4 a_ = *(const float4*)&As[kk][ty << 2];
            float4 b_ = *(const float4*)&Bs[kk][tx << 2];
            #pragma unroll
            for (int r = 0; r < 4; ++r) {
                float av = r == 0 ? a_.x : r == 1 ? a_.y : r == 2 ? a_.z : a_.w;
                acc[r][0] = fmaf(av, b_.x, acc[r][0]);
                acc[r][1] = fmaf(av, b_.y, acc[r][1]);
                acc[r][2] = fmaf(av, b_.z, acc[r][2]);
                acc[r][3] = fmaf(av, b_.w, acc[r][3]);
            }
        }
        __syncthreads();
    }
    const int k4 = j0 + (tx << 2);
    #pragma unroll
    for (int r = 0; r < 4; ++r) {
        const int row = i0 + (ty << 2) + r;
        *(float4*)&adb[(size_t)row * MOUT + k4] =
            make_float4(acc[r][0], acc[r][1], acc[r][2], acc[r][3]);
        half4 h, l;
        #pragma unroll
        for (int e = 0; e < 4; ++e) {
            _Float16 hh = (_Float16)acc[r][e];
            h[e] = hh;
            l[e] = (_Float16)(acc[r][e] - (float)hh);
        }
        size_t off = swz32(row, k4);
        *(half4*)&bh[off] = h;
        *(half4*)&bl[off] = l;
    }
}

// ---------------------------------------------------------------------------
// FUSED persistent ADMM loop (round-8 exact, best verified: 1040us).
// 256 blocks x 512 threads (1/CU): 8 stripes (mt, 128 rows) x 32 nt (32 n).
// Minv slice 128 KB LDS once. Wave (bt,kh): 32x32 tile x K-half; halves
// combine via conflict-free sc4 LDS. Convergence decision for iter it-1 is
// computed redundantly by EVERY block during iter it's GEMM (part buffer is
// ping-ponged so read-old/write-new is race-free), published in block-local
// sticky LDS mask sfroz[128]. No global solved array, no phase B, no 2nd
// barrier. Early exit: block-local ballot over sfroz (stripe-uniform).
// Rows converging at the final iteration: one post-loop decision pass.
// ---------------------------------------------------------------------------
__global__ __launch_bounds__(512, 1)
void admm_loop(const float* __restrict__ adb, float* __restrict__ part,
               _Float16* __restrict__ bh0, _Float16* __restrict__ bl0,
               _Float16* __restrict__ bh1, _Float16* __restrict__ bl1,
               const _Float16* __restrict__ Th, const _Float16* __restrict__ Tl,
               float* __restrict__ enc, _Float16* __restrict__ ench,
               _Float16* __restrict__ encl, int* __restrict__ bar) {
    const int bid = blockIdx.x;
    const int tid = threadIdx.x, lane = tid & 63;
    const int w = tid >> 6;                // wave 0..7
    const int bt = w >> 1;                 // batch tile 0..3
    const int kh = w & 1;                  // K-half
    const int mt = bid & 7, nt = bid >> 3;
    const int n0 = nt << 5, m0 = mt << 7;
    const int hn = lane >> 5;              // n-half selector
    const int brow = m0 + (bt << 5) + (lane & 31);
    const int btile = (mt << 2) + bt;      // beff 32-row tile

    __shared__ _Float16 Bs[128 * 512];     // 128 KB Minv slice: chunk=kc*2+hl
    __shared__ float4 sc4[4][4][64];       // 16 KB k-half exchange, lane-contig
    __shared__ unsigned char sfroz[128];   // sticky frozen mask (block-local)

    if (tid < 128) sfroz[tid] = 0;

    // one-time Minv staging: 128 chunks of 1 KB (16 per wave)
    #pragma unroll
    for (int q = 0; q < 16; ++q) {
        const int chunk = (w << 4) + q;
        const int kc = chunk >> 1, hl = chunk & 1;
        const _Float16* src = (hl ? Tl : Th) +
            (((size_t)((nt << 6) + kc)) << 9) + ((size_t)lane << 3);
        __builtin_amdgcn_global_load_lds(
            (const __attribute__((address_space(1))) void*)src,
            (__attribute__((address_space(3))) void*)&Bs[(size_t)chunk << 9],
            16, 0, 0);
    }
    __syncthreads();

    int* gcnt = bar + (mt << 5);
    int* ggen = bar + (mt << 5) + 16;

    // decision geometry: wave handles rows m0+w*16..+15; 4 lanes per row
    const int drow_l = (w << 4) + (lane >> 2);     // row-in-stripe 0..127
    const int dq = (lane & 3) << 3;                // first float2 col
    const float* dbase0 = part + ((((size_t)(m0 + drow_l)) << 6) + (dq << 1));

    // register-resident state (kh==0 waves): n = n0 + 8*r4 + 4*hn + e
    float treg[16] = {};
    float adbreg[16];
    #pragma unroll
    for (int r4 = 0; r4 < 4; ++r4) {
        const int nb = n0 + (r4 << 3) + (hn << 2);
        float4 a4 = *(const float4*)&adb[(size_t)brow * MOUT + nb];
        adbreg[(r4 << 2) + 0] = a4.x; adbreg[(r4 << 2) + 1] = a4.y;
        adbreg[(r4 << 2) + 2] = a4.z; adbreg[(r4 << 2) + 3] = a4.w;
    }

    int it = 0;
    for (; it < MAX_ITERS; ++it) {
        const _Float16* rbh = (it & 1) ? bh1 : bh0;
        const _Float16* rbl = (it & 1) ? bl1 : bl0;
        _Float16* wbh = (it & 1) ? bh0 : bh1;
        _Float16* wbl = (it & 1) ? bl0 : bl1;
        const int pw = it & 1;             // part write buffer

        // ---- issue decision loads (iter it-1 partials, buffer !pw) early
        float4 dp0, dp1, dp2, dp3;
        if (it) {
            const float* pb = dbase0 + ((size_t)(pw ^ 1) << 16);
            dp0 = *(const float4*)(pb + 0);
            dp1 = *(const float4*)(pb + 4);
            dp2 = *(const float4*)(pb + 8);
            dp3 = *(const float4*)(pb + 12);
        }

        // ============ PHASE A: 32x32x16 gemm (3 independent chains) ========
        floatx16 accA = {}, accB = {}, accC = {};
        const int kc0 = kh << 5;
        #pragma unroll 4
        for (int kc = kc0; kc < kc0 + 32; ++kc) {
            const size_t boff =
                (((size_t)(btile << 6) + kc) << 9) + ((size_t)lane << 3);
            const half8 bhf = *(const half8*)&rbh[boff];
            const half8 blf = *(const half8*)&rbl[boff];
            const half8 ah = *(const half8*)&Bs[((kc << 1) << 9) + (lane << 3)];
            const half8 al = *(const half8*)&Bs[(((kc << 1) | 1) << 9) + (lane << 3)];
            accA = __builtin_amdgcn_mfma_f32_32x32x16_f16(al, bhf, accA, 0, 0, 0);
            accB = __builtin_amdgcn_mfma_f32_32x32x16_f16(ah, blf, accB, 0, 0, 0);
            accC = __builtin_amdgcn_mfma_f32_32x32x16_f16(ah, bhf, accC, 0, 0, 0);
        }
        if (kh) {   // publish k-half-1 partial (conflict-free layout)
            #pragma unroll
            for (int r4 = 0; r4 < 4; ++r4) {
                float4 v;
                v.x = (accA[(r4 << 2) + 0] + accB[(r4 << 2) + 0]) + accC[(r4 << 2) + 0];
                v.y = (accA[(r4 << 2) + 1] + accB[(r4 << 2) + 1]) + accC[(r4 << 2) + 1];
                v.z = (accA[(r4 << 2) + 2] + accB[(r4 << 2) + 2]) + accC[(r4 << 2) + 2];
                v.w = (accA[(r4 << 2) + 3] + accB[(r4 << 2) + 3]) + accC[(r4 << 2) + 3];
                sc4[bt][r4][lane] = v;
            }
        }

        // ---- decision reduce for iter it-1 (hidden under GEMM latency)
        if (it) {
            float rdx = ((dp0.x + dp0.z) + (dp1.x + dp1.z)) +
                        ((dp2.x + dp2.z) + (dp3.x + dp3.z));
            float rx  = ((dp0.y + dp0.w) + (dp1.y + dp1.w)) +
                        ((dp2.y + dp2.w) + (dp3.y + dp3.w));
            rdx += __shfl_xor(rdx, 1); rdx += __shfl_xor(rdx, 2);
            rx  += __shfl_xor(rx, 1);  rx  += __shfl_xor(rx, 2);
            if (rdx < TOLF * TOLF * rx && (lane & 3) == 0)
                sfroz[drow_l] = 1;         // sticky set, never cleared
        }
        __syncthreads();                   // publishes sc4 AND sfroz

        // ---- stripe-uniform exact early exit (block-local ballot)
        bool f0 = sfroz[lane] != 0, f1 = sfroz[64 + lane] != 0;
        if ((__ballot(f0) & __ballot(f1)) == ~0ull) break;

        // ============ fused update (kh==0 waves, active rows) ==============
        const bool sflag = sfroz[(bt << 5) + (lane & 31)] != 0;
        if (kh == 0 && !sflag) {
            float dx2 = 0.f, x2 = 0.f;
            #pragma unroll
            for (int r4 = 0; r4 < 4; ++r4) {
                float4 p1 = sc4[bt][r4][lane];
                float pa[4] = {p1.x, p1.y, p1.z, p1.w};
                half4 h, l;
                #pragma unroll
                for (int e = 0; e < 4; ++e) {
                    const int r = (r4 << 2) + e;
                    float s0 = (accA[r] + accB[r]) + accC[r];
                    float xk = s0 + pa[e];            // p0 + p1 (ref order)
                    float t_ = treg[r];
                    float vprev = shrinkf(t_);
                    float uu = t_ - vprev;
                    float tn = xk + uu;               // = u + xk
                    float vv = shrinkf(tn);
                    float un = tn - vv;               // u_new
                    float d = vv - vprev;
                    dx2 += d * d;
                    x2 += vv * vv;
                    treg[r] = tn;
                    float nb_ = (adbreg[r] + vv) - un;
                    _Float16 hh = (_Float16)nb_;
                    h[e] = hh;
                    l[e] = (_Float16)(nb_ - (float)hh);
                }
                size_t off = swz32(brow, n0 + (r4 << 3) + (hn << 2));
                *(half4*)&wbh[off] = h;
                *(half4*)&wbl[off] = l;
            }
            // row partial over block's 32 n: lane^32 holds the other n-half
            dx2 += __shfl_xor(dx2, 32);
            x2  += __shfl_xor(x2, 32);
            if (hn == 0)
                *(float2*)&part[(((size_t)pw << 16) +
                                 (((size_t)brow) << 6) + ((size_t)nt << 1))] =
                    make_float2(dx2, x2);
        }
        gbar32(gcnt, ggen, it + 1);
    }

    // ---- final pending decision (rows converging at the last iteration)
    if (it == MAX_ITERS) {
        const float* pb = dbase0 + ((size_t)((MAX_ITERS - 1) & 1) << 16);
        float4 dp0 = *(const float4*)(pb + 0);
        float4 dp1 = *(const float4*)(pb + 4);
        float4 dp2 = *(const float4*)(pb + 8);
        float4 dp3 = *(const float4*)(pb + 12);
        float rdx = ((dp0.x + dp0.z) + (dp1.x + dp1.z)) +
                    ((dp2.x + dp2.z) + (dp3.x + dp3.z));
        float rx  = ((dp0.y + dp0.w) + (dp1.y + dp1.w)) +
                    ((dp2.y + dp2.w) + (dp3.y + dp3.w));
        rdx += __shfl_xor(rdx, 1); rdx += __shfl_xor(rdx, 2);
        rx  += __shfl_xor(rx, 1);  rx  += __shfl_xor(rx, 2);
        if (rdx < TOLF * TOLF * rx && (lane & 3) == 0)
            sfroz[drow_l] = 1;
        __syncthreads();
    }

    // ============ final flush: enc = shrink(t_frozen) for solved rows ======
    if (kh == 0 && sfroz[(bt << 5) + (lane & 31)]) {
        #pragma unroll
        for (int r4 = 0; r4 < 4; ++r4) {
            const int nb = n0 + (r4 << 3) + (hn << 2);
            float va[4]; half4 h, l;
            #pragma unroll
            for (int e = 0; e < 4; ++e) {
                float vv = shrinkf(treg[(r4 << 2) + e]);
                va[e] = vv;
                _Float16 hh = (_Float16)vv;
                h[e] = hh;
                l[e] = (_Float16)(vv - (float)hh);
            }
            *(float4*)&enc[(size_t)brow * MOUT + nb] =
                make_float4(va[0], va[1], va[2], va[3]);
            size_t off = swz(brow, nb);        // dec path keeps 16x16 swizzle
            *(half4*)&ench[off] = h;
            *(half4*)&encl[off] = l;
        }
    }
}

// ---------------------------------------------------------------------------
// dec = enc @ w, split-f16 MFMA (16x16 path), runs ONCE. Unchanged.
// ---------------------------------------------------------------------------
__global__ __launch_bounds__(256, 2)
void mfma_dec(const _Float16* __restrict__ Ahg, const _Float16* __restrict__ Alg,
              const _Float16* __restrict__ Bhg, const _Float16* __restrict__ Blg,
              float* __restrict__ out) {
    constexpr int NSTR = NIN;              // 512
    constexpr int NT = NSTR / 128;         // 4
    const int bid = blockIdx.x;
    const int c = bid & 7, t = bid >> 3;
    const int mt = t / NT, nt = t % NT;
    const int tid = threadIdx.x, lane = tid & 63;

    __shared__ _Float16 Ash[64 * 512];     // 64 KB

    const int wv = tid >> 6;
    const int wm = (tid >> 7) & 1, wn = (tid >> 6) & 1;
    const int kf0 = c << 2;

    #pragma unroll
    for (int i = 0; i < 16; ++i) {
        const int chunk = (wv << 4) + i;
        const int rt = chunk >> 3, kc = (chunk >> 1) & 3, hl = chunk & 1;
        const _Float16* src = (hl ? Alg : Ahg) +
            ((((size_t)((mt << 3) + rt) * 32 + kf0 + kc) << 9) + ((size_t)lane << 3));
        __builtin_amdgcn_global_load_lds(
            (const __attribute__((address_space(1))) void*)src,
            (__attribute__((address_space(3))) void*)&Ash[(size_t)chunk << 9],
            16, 0, 0);
    }
    __syncthreads();

    const int ct0 = nt * 8 + (wn << 2);
    const _Float16* pBh = Bhg + ((((size_t)ct0 * 32 + kf0) * 64 + lane) << 3);
    const _Float16* pBl = Blg + ((((size_t)ct0 * 32 + kf0) * 64 + lane) << 3);

    floatx4 acc[4][4] = {};
    #pragma unroll
    for (int s = 0; s < 4; ++s) {
        half8 bhf[4], blf[4];
        #pragma unroll
        for (int j = 0; j < 4; ++j) {
            bhf[j] = *(const half8*)(pBh + ((size_t)j << 14) + ((size_t)s << 9));
            blf[j] = *(const half8*)(pBl + ((size_t)j << 14) + ((size_t)s << 9));
        }
        half8 ah[4], al[4];
        #pragma unroll
        for (int i = 0; i < 4; ++i) {
            const int rt = (wm << 2) + i;
            ah[i] = *(const half8*)&Ash[((((rt << 2) + s) << 1) << 9) + (lane << 3)];
            al[i] = *(const half8*)&Ash[(((((rt << 2) + s) << 1) + 1) << 9) + (lane << 3)];
        }
        #pragma unroll
        for (int i = 0; i < 4; ++i)
            #pragma unroll
            for (int j = 0; j < 4; ++j) {
                acc[i][j] = __builtin_amdgcn_mfma_f32_16x16x32_f16(
                    ah[i], blf[j], acc[i][j], 0, 0, 0);
                acc[i][j] = __builtin_amdgcn_mfma_f32_16x16x32_f16(
                    al[i], bhf[j], acc[i][j], 0, 0, 0);
                acc[i][j] = __builtin_amdgcn_mfma_f32_16x16x32_f16(
                    ah[i], bhf[j], acc[i][j], 0, 0, 0);
            }
    }

    const int orow = (lane >> 4) << 2;
    #pragma unroll
    for (int i = 0; i < 4; ++i) {
        const int gr = (mt << 7) + (wm << 6) + (i << 4) + orow;
        #pragma unroll
        for (int j = 0; j < 4; ++j) {
            const int gc = nt * 128 + (wn << 6) + (j << 4) + (lane & 15);
            #pragma unroll
            for (int r = 0; r < 4; ++r)
                atomicAdd(&out[(size_t)(gr + r) * NSTR + gc], acc[i][j][r]);
        }
    }
}

// ---------------------------------------------------------------------------
extern "C" void kernel_launch(void* const* d_in, const int* in_sizes, int n_in,
                              void* d_out, int out_size, void* d_ws, size_t ws_size,
                              hipStream_t stream) {
    const float* x    = (const float*)d_in[0];
    const float* w    = (const float*)d_in[1];
    const float* Minv = (const float*)d_in[2];

    float* enc = (float*)d_out;          // encoded: 1024*1024
    float* dec = enc + MM;               // decoded: 1024*512

    // ws (floats): adb MM | beff buf1 (bh1,bl1) | part 2x256KB (in 2*MM) |
    // halves: bh0,bl0,Th,Tl,ench,encl MM, wsh,wsl MM/2 | barrier words.
    float* ws  = (float*)d_ws;
    float* adb = ws;
    _Float16* bh1 = (_Float16*)(ws + (size_t)MM);   // ping-pong buffer 1
    _Float16* bl1 = bh1 + (size_t)MM;
    float* part = ws + 2 * (size_t)MM;              // 2 x [1024][32] float2

    _Float16* bh0  = (_Float16*)(ws + 4 * (size_t)MM);
    _Float16* bl0  = bh0 + (size_t)MM;
    _Float16* Th   = bl0 + (size_t)MM;
    _Float16* Tl   = Th + (size_t)MM;
    _Float16* ench = Tl + (size_t)MM;
    _Float16* encl = ench + (size_t)MM;
    _Float16* wsh  = encl + (size_t)MM;
    _Float16* wsl  = wsh + (size_t)(NIN * MOUT);
    int* solved    = (int*)(wsl + (size_t)(NIN * MOUT));
    int* bar       = solved + 1088;      // 8 stripes x 32 ints (128 B) apart

    zero_init<<<(MM + 255) / 256, 256, 0, stream>>>((float*)bh1, enc, dec,
                                                    (float*)ench, (float*)encl,
                                                    solved);
    split_minv<<<512, 256, 0, stream>>>(Minv, Th, Tl);
    split_w<<<256, 256, 0, stream>>>(w, wsh, wsl);
    gemm_adb<<<256, 256, 0, stream>>>(x, w, adb, bh0, bl0);

    void* cargs[] = {(void*)&adb, (void*)&part,
                     (void*)&bh0, (void*)&bl0, (void*)&bh1, (void*)&bl1,
                     (void*)&Th,  (void*)&Tl,
                     (void*)&enc, (void*)&ench, (void*)&encl, (void*)&bar};
    // Cooperative launch used ONLY as a co-residency guarantee (deadlock
    // safety for the spin barriers); no grid.sync() is ever called.
    hipLaunchCooperativeKernel(reinterpret_cast<void*>(admm_loop),
                               dim3(256), dim3(512), cargs, 0, stream);

    mfma_dec<<<256, 256, 0, stream>>>(ench, encl, wsh, wsl, dec);
}